// Round 9
// baseline (396.407 us; speedup 1.0000x reference)
//
#include <hip/hip_runtime.h>

typedef unsigned short u16;
typedef short bf16x8 __attribute__((ext_vector_type(8)));
typedef float f32x4 __attribute__((ext_vector_type(4)));

#define GLB __attribute__((address_space(1)))
#define LDSAS __attribute__((address_space(3)))
#define WAITV(n) asm volatile("s_waitcnt vmcnt(" #n ")" ::: "memory")

constexpr int S = 2048, D = 4096, NH = 32, NHK = 8, DHD = 128;
constexpr int NQKV = 6144;  // 4096 q + 1024 k + 1024 v

__device__ __forceinline__ u16 f2b(float f) {
    union { float f; unsigned u; } v; v.f = f;
    return (u16)((v.u + 0x7fffu + ((v.u >> 16) & 1u)) >> 16);
}
__device__ __forceinline__ float b2f(u16 b) {
    union { unsigned u; float f; } v; v.u = ((unsigned)b) << 16;
    return v.f;
}
__device__ __forceinline__ void gload16(const void* g, void* l) {
    __builtin_amdgcn_global_load_lds((const GLB unsigned int*)g,
                                     (LDSAS unsigned int*)l, 16, 0, 0);
}
#if __has_builtin(__builtin_amdgcn_exp2f)
__device__ __forceinline__ float exp2fast(float x) { return __builtin_amdgcn_exp2f(x); }
#else
__device__ __forceinline__ float exp2fast(float x) { return __expf(0.6931471805599453f * x); }
#endif

// Accurate sin/cos for large args: reduce to revolutions in [0,1), then v_sin/v_cos.
__device__ __forceinline__ void sincos_big(float ang, float* sn, float* cs) {
#if __has_builtin(__builtin_amdgcn_sinf) && __has_builtin(__builtin_amdgcn_cosf)
    float rev = ang * 0.15915494309189535f;  // 1/(2*pi)
    rev = rev - floorf(rev);                 // [0,1)
    *sn = __builtin_amdgcn_sinf(rev);
    *cs = __builtin_amdgcn_cosf(rev);
#else
    *sn = sinf(ang);
    *cs = cosf(ang);
#endif
}

// ---------------- f32 -> bf16 elementwise (8/thread) ----------------
__global__ __launch_bounds__(256) void cvt_x(const float* __restrict__ in,
                                             u16* __restrict__ out, int n8) {
    int i = blockIdx.x * 256 + threadIdx.x;
    if (i >= n8) return;
    const float4* p = (const float4*)in + (size_t)i * 2;
    float4 a = p[0], b = p[1];
    uint4 o;
    o.x = f2b(a.x) | ((unsigned)f2b(a.y) << 16);
    o.y = f2b(a.z) | ((unsigned)f2b(a.w) << 16);
    o.z = f2b(b.x) | ((unsigned)f2b(b.y) << 16);
    o.w = f2b(b.z) | ((unsigned)f2b(b.w) << 16);
    *(uint4*)(out + (size_t)i * 8) = o;
}

// ---------------- f32 [R][C] -> bf16 [C][R] ----------------
__global__ __launch_bounds__(256) void tconv(const float* __restrict__ in,
                                             u16* __restrict__ out, int R, int C) {
    __shared__ float t[64][65];
    int r0 = blockIdx.y * 64, c0 = blockIdx.x * 64;
    int tx = threadIdx.x & 63, ty = threadIdx.x >> 6;
#pragma unroll
    for (int i = 0; i < 64; i += 4)
        t[ty + i][tx] = in[(size_t)(r0 + ty + i) * C + c0 + tx];
    __syncthreads();
#pragma unroll
    for (int i = 0; i < 64; i += 4)
        out[(size_t)(c0 + ty + i) * R + r0 + tx] = f2b(t[tx][ty + i]);
}

// ---------------- bf16 V (QKV cols 5120..6143) -> Vt [hk][d][s] ----------------
__global__ __launch_bounds__(256) void vtrans(const u16* __restrict__ QKV,
                                              u16* __restrict__ Vt) {
    __shared__ u16 t[64][65];
    int hk = blockIdx.z;
    int s0 = blockIdx.x * 64, d0 = blockIdx.y * 64;
    int tx = threadIdx.x & 63, ty = threadIdx.x >> 6;
#pragma unroll
    for (int i = 0; i < 64; i += 4)
        t[ty + i][tx] = QKV[(size_t)(s0 + ty + i) * NQKV + 5120 + hk * 128 + d0 + tx];
    __syncthreads();
#pragma unroll
    for (int i = 0; i < 64; i += 4)
        Vt[(size_t)hk * (128 * 2048) + (size_t)(d0 + ty + i) * 2048 + s0 + tx] = t[tx][ty + i];
}

// ---------------- RoPE in place, bf16, stride NQKV; scale folded in ----------------
template <int NHEADS>
__global__ __launch_bounds__(256) void rope2(u16* __restrict__ T,
                                             const int* __restrict__ pos, float scale) {
    int idx = blockIdx.x * 256 + threadIdx.x;
    int d = idx & 63;
    int h = (idx >> 6) & (NHEADS - 1);
    int s = idx >> (6 + (NHEADS == 32 ? 5 : 3));
    float p = (float)pos[s];
    float inv = __expf(-(float)d * 0.14391156531310576f);  // 10000^(-d/64)
    float ang = p * inv;
    float sn, cs;
    sincos_big(ang, &sn, &cs);
    size_t base = (size_t)s * NQKV + h * 128 + d;
    float x1 = b2f(T[base]), x2 = b2f(T[base + 64]);
    T[base]      = f2b((x1 * cs - x2 * sn) * scale);
    T[base + 64] = f2b((x2 * cs + x1 * sn) * scale);
}

// ---------------- GEMM P: 256xBN, BK=64, 8 waves, m201-style 4-phase pipeline ----------------
// Per K-tile: ph0 {read af03+bf[0..NJ-2] | stage A0' | bar | lgkm0 | MFMA | bar}
//             ph1 {read bf[NJ-1] | stage B' | bar | lgkm0 | MFMA | WAITV(2+NBU) | bar}
//             ph2 {read af47 | bar | lgkm0 | MFMA | bar}
//             ph3 {stage A1' | MFMA | WAITV(2) | bar}
// Issue order A0,B...,A1 => each wait retires only loads >=2 phases old (never a drain).
// Wait+barrier precedes the consuming phase's reads (cross-wave LDS visibility).
template <int BN, bool BF16OUT>
__global__ __launch_bounds__(512, 2) void gemmP(const u16* __restrict__ A,
                                                const u16* __restrict__ Bt,
                                                void* __restrict__ Cout,
                                                int N, int K) {
    constexpr int NJ = BN / 64;    // n-frags per wave (3 or 2)
    constexpr int NBU = BN / 64;   // 64-row B stage units
    constexpr int WCOL = BN / 4;   // cols per wave
    __shared__ u16 Asm[2][256 * 64];
    __shared__ u16 Bsm[2][BN * 64];
    const int cpx = (int)gridDim.x >> 3;
    const int b = ((int)blockIdx.x & 7) * cpx + ((int)blockIdx.x >> 3);
    const int nbx = N / BN;
    const int by = b / nbx, bx = b - by * nbx;
    const int m0 = by * 256, n0 = bx * BN;
    const int tid = threadIdx.x, lane = tid & 63, wave = tid >> 6;
    const int l15 = lane & 15, l4 = lane >> 4;
    const int wm = wave >> 2, wn = wave & 3;
    f32x4 acc[8][NJ] = {};

    auto stA = [&](int t, int buf, int half) {
#pragma unroll
        for (int u = 0; u < 2; ++u) {
            int s = u * 512 + tid;
            int row = s >> 3, cs = (s & 7) ^ (row & 7);
            gload16(A + (size_t)(m0 + half * 128 + row) * K + t * 64 + cs * 8,
                    &Asm[buf][half * 8192 + s * 8]);
        }
    };
    auto stB1 = [&](int t, int buf, int u0) {  // one 64-row unit, 1 load/thread
        int row = u0 * 64 + (tid >> 3);
        int cs = (tid & 7) ^ (row & 7);
        gload16(Bt + (size_t)(n0 + row) * K + t * 64 + cs * 8,
                &Bsm[buf][u0 * 4096 + tid * 8]);
    };

    const int NT = K >> 6;
    // prologue: tile 0 in issue order A0, B..., A1; retire A0+B before first reads
    stA(0, 0, 0);
#pragma unroll
    for (int u = 0; u < NBU; ++u) stB1(0, 0, u);
    stA(0, 0, 1);
    WAITV(2);
    __builtin_amdgcn_s_barrier();

    bf16x8 af[4][2], bf[NJ][2];
#pragma unroll 1
    for (int t = 0; t < NT; ++t) {
        const int cur = t & 1, nxt = cur ^ 1;
        const bool pre = (t + 1 < NT);
        const u16* Ab = &Asm[cur][0];
        const u16* Bb = &Bsm[cur][0];
        // ================= phase 0: af03 + bf[0..NJ-2]; stage A0' =================
#pragma unroll
        for (int i = 0; i < 4; ++i)
#pragma unroll
            for (int kk = 0; kk < 2; ++kk) {
                int row = wm * 64 + i * 16 + l15;
                int cc = (kk * 4 + l4) ^ (row & 7);
                af[i][kk] = *(const bf16x8*)(Ab + row * 64 + cc * 8);
            }
#pragma unroll
        for (int j = 0; j < NJ - 1; ++j)
#pragma unroll
            for (int kk = 0; kk < 2; ++kk) {
                int row = wn * WCOL + j * 16 + l15;
                int cc = (kk * 4 + l4) ^ (row & 7);
                bf[j][kk] = *(const bf16x8*)(Bb + row * 64 + cc * 8);
            }
        if (pre) stA(t + 1, nxt, 0);
        __builtin_amdgcn_s_barrier();
        asm volatile("s_waitcnt lgkmcnt(0)" ::: "memory");
        __builtin_amdgcn_s_setprio(1);
#pragma unroll
        for (int i = 0; i < 4; ++i)
#pragma unroll
            for (int j = 0; j < NJ - 1; ++j)
#pragma unroll
                for (int kk = 0; kk < 2; ++kk)
                    acc[i][j] = __builtin_amdgcn_mfma_f32_16x16x32_bf16(af[i][kk], bf[j][kk], acc[i][j], 0, 0, 0);
        __builtin_amdgcn_s_setprio(0);
        __builtin_amdgcn_s_barrier();
        // ================= phase 1: bf[NJ-1]; stage B'; retire A1(t) =================
#pragma unroll
        for (int kk = 0; kk < 2; ++kk) {
            int row = wn * WCOL + (NJ - 1) * 16 + l15;
            int cc = (kk * 4 + l4) ^ (row & 7);
            bf[NJ - 1][kk] = *(const bf16x8*)(Bb + row * 64 + cc * 8);
        }
        if (pre) {
#pragma unroll
            for (int u = 0; u < NBU; ++u) stB1(t + 1, nxt, u);
        }
        __builtin_amdgcn_s_barrier();
        asm volatile("s_waitcnt lgkmcnt(0)" ::: "memory");
        __builtin_amdgcn_s_setprio(1);
#pragma unroll
        for (int i = 0; i < 4; ++i)
#pragma unroll
            for (int kk = 0; kk < 2; ++kk)
                acc[i][NJ - 1] = __builtin_amdgcn_mfma_f32_16x16x32_bf16(af[i][kk], bf[NJ - 1][kk], acc[i][NJ - 1], 0, 0, 0);
        __builtin_amdgcn_s_setprio(0);
        if (pre) { if constexpr (NBU == 3) WAITV(5); else WAITV(4); }
        else WAITV(0);
        __builtin_amdgcn_s_barrier();
        // ================= phase 2: af47 (half1) =================
#pragma unroll
        for (int i = 0; i < 4; ++i)
#pragma unroll
            for (int kk = 0; kk < 2; ++kk) {
                int row = wm * 64 + i * 16 + l15;
                int cc = (kk * 4 + l4) ^ (row & 7);
                af[i][kk] = *(const bf16x8*)(Ab + 8192 + row * 64 + cc * 8);
            }
        __builtin_amdgcn_s_barrier();
        asm volatile("s_waitcnt lgkmcnt(0)" ::: "memory");
        __builtin_amdgcn_s_setprio(1);
#pragma unroll
        for (int i = 0; i < 4; ++i)
#pragma unroll
            for (int j = 0; j < NJ - 1; ++j)
#pragma unroll
                for (int kk = 0; kk < 2; ++kk)
                    acc[i + 4][j] = __builtin_amdgcn_mfma_f32_16x16x32_bf16(af[i][kk], bf[j][kk], acc[i + 4][j], 0, 0, 0);
        __builtin_amdgcn_s_setprio(0);
        __builtin_amdgcn_s_barrier();
        // ================= phase 3: stage A1'; retire A0'+B' =================
        if (pre) stA(t + 1, nxt, 1);
        __builtin_amdgcn_s_setprio(1);
#pragma unroll
        for (int i = 0; i < 4; ++i)
#pragma unroll
            for (int kk = 0; kk < 2; ++kk)
                acc[i + 4][NJ - 1] = __builtin_amdgcn_mfma_f32_16x16x32_bf16(af[i][kk], bf[NJ - 1][kk], acc[i + 4][NJ - 1], 0, 0, 0);
        __builtin_amdgcn_s_setprio(0);
        if (pre) WAITV(2);
        __builtin_amdgcn_s_barrier();
    }
    // epilogue
#pragma unroll
    for (int i = 0; i < 8; ++i)
#pragma unroll
        for (int j = 0; j < NJ; ++j) {
            int col = n0 + wn * WCOL + j * 16 + l15;
            int rowb = m0 + (i < 4 ? wm * 64 + i * 16 : 128 + wm * 64 + (i - 4) * 16) + l4 * 4;
#pragma unroll
            for (int r = 0; r < 4; ++r) {
                if (BF16OUT)
                    ((u16*)Cout)[(size_t)(rowb + r) * N + col] = f2b(acc[i][j][r]);
                else
                    ((float*)Cout)[(size_t)(rowb + r) * N + col] = acc[i][j][r];
            }
        }
}

// ---------------- Flash attention v3: balanced tile pairs ----------------
__global__ __launch_bounds__(256) void attn3(const u16* __restrict__ QKV,
                                             const u16* __restrict__ Vt,
                                             u16* __restrict__ O) {
    __shared__ u16 Ksm[2][64 * 128];  // [kv][d-chunk swz]
    __shared__ u16 Vsm[2][128 * 64];  // [d][kv-chunk swz]
    __shared__ u16 Psm[4][16 * 64];   // per-wave P tile, swz
    const int orig = blockIdx.x;
    const int swz = (orig & 7) * 64 + (orig >> 3);   // 512 = 8*64, bijective
    const int h = swz >> 4, p = swz & 15;
    const int hk = h >> 2;
    const int tid = threadIdx.x, wave = tid >> 6, lane = tid & 63;
    const int l15 = lane & 15, l4 = lane >> 4;
    const u16* Qp = QKV + h * 128;
    const u16* Kp = QKV + 4096 + hk * 128;
    const u16* Vp = Vt + (size_t)hk * (128 * 2048);

    auto stage = [&](int kb, int b) {
#pragma unroll
        for (int it = 0; it < 4; ++it) {
            int L = it * 256 + tid;
            int krow = L >> 4, kslot = L & 15;
            int kcs = (kslot & 8) | ((kslot ^ krow) & 7);
            gload16(Kp + (size_t)(kb * 64 + krow) * NQKV + kcs * 8, &Ksm[b][L * 8]);
            int vrow = L >> 3, vslot = L & 7;
            int vcs = (vslot ^ vrow) & 7;
            gload16(Vp + (size_t)vrow * 2048 + kb * 64 + vcs * 8, &Vsm[b][L * 8]);
        }
    };

#pragma unroll 1
    for (int pass = 0; pass < 2; ++pass) {
        const int qt = pass ? p : 31 - p;
        const int qr0 = qt * 64 + wave * 16;
        const int nkb = qt + 1;

        bf16x8 qf[4];
        {
            const u16* qrow = Qp + (size_t)(qr0 + l15) * NQKV;
#pragma unroll
            for (int c = 0; c < 4; ++c)
                qf[c] = *(const bf16x8*)(qrow + c * 32 + l4 * 8);
        }
        float mrow[4], lsum[4];
#pragma unroll
        for (int r = 0; r < 4; ++r) { mrow[r] = -1e30f; lsum[r] = 0.f; }
        f32x4 o[8] = {};

        stage(0, 0);
#pragma unroll 1
        for (int kb = 0; kb < nkb; ++kb) {
            const int cur = kb & 1;
            if (kb + 1 < nkb) {
                stage(kb + 1, cur ^ 1);
                asm volatile("s_waitcnt vmcnt(8)" ::: "memory");
            } else {
                asm volatile("s_waitcnt vmcnt(0)" ::: "memory");
            }
            __builtin_amdgcn_s_barrier();

            if (kb * 64 <= qr0 + 15) {  // wave has unmasked work
                const u16* Kb_ = Ksm[cur];
                const u16* Vb_ = Vsm[cur];
                const bool diag = (kb * 64 + 63 > qr0);
                // ---- S = Q K^T (log2 domain) ----
                f32x4 sc[4] = {};
#pragma unroll
                for (int f = 0; f < 4; ++f) {
                    const int kv = f * 16 + l15;
#pragma unroll
                    for (int c = 0; c < 4; ++c) {
                        int cd = c * 4 + l4;
                        int cpos = (cd & 8) | ((cd ^ kv) & 7);
                        bf16x8 kf = *(const bf16x8*)(Kb_ + kv * 128 + cpos * 8);
                        sc[f] = __builtin_amdgcn_mfma_f32_16x16x32_bf16(qf[c], kf, sc[f], 0, 0, 0);
                    }
                }
                if (diag) {
#pragma unroll
                    for (int f = 0; f < 4; ++f) {
                        int col = kb * 64 + f * 16 + l15;
#pragma unroll
                        for (int r = 0; r < 4; ++r) {
                            int row = qr0 + l4 * 4 + r;
                            if (col > row) sc[f][r] = -1e30f;
                        }
                    }
                }
                float bm[4];
#pragma unroll
                for (int r = 0; r < 4; ++r)
                    bm[r] = fmaxf(fmaxf(sc[0][r], sc[1][r]), fmaxf(sc[2][r], sc[3][r]));
#pragma unroll
                for (int msk = 1; msk < 16; msk <<= 1)
#pragma unroll
                    for (int r = 0; r < 4; ++r) bm[r] = fmaxf(bm[r], __shfl_xor(bm[r], msk));

                bool need = false;
#pragma unroll
                for (int r = 0; r < 4; ++r) need = need || (bm[r] > mrow[r] + 8.0f);
                if (__any((int)need)) {  // T13 defer-rescale, per-row alpha
                    float al[4];
#pragma unroll
                    for (int r = 0; r < 4; ++r) {
                        float mn = fmaxf(mrow[r], bm[r]);
                        al[r] = exp2fast(mrow[r] - mn);
                        mrow[r] = mn;
                        lsum[r] *= al[r];
                    }
#pragma unroll
                    for (int n = 0; n < 8; ++n)
#pragma unroll
                        for (int r = 0; r < 4; ++r) o[n][r] *= al[r];
                }
                float rs[4] = {0.f, 0.f, 0.f, 0.f};
#pragma unroll
                for (int f = 0; f < 4; ++f) {
#pragma unroll
                    for (int r = 0; r < 4; ++r) {
                        float pw = exp2fast(sc[f][r] - mrow[r]);
                        rs[r] += pw;
                        int q = l4 * 4 + r;
                        int kvc = f * 2 + (l15 >> 3);
                        int slot = (kvc ^ q) & 7;
                        Psm[wave][q * 64 + slot * 8 + (l15 & 7)] = f2b(pw);
                    }
                }
#pragma unroll
                for (int msk = 1; msk < 16; msk <<= 1)
#pragma unroll
                    for (int r = 0; r < 4; ++r) rs[r] += __shfl_xor(rs[r], msk);
#pragma unroll
                for (int r = 0; r < 4; ++r) lsum[r] += rs[r];

                asm volatile("s_waitcnt lgkmcnt(0)" ::: "memory");
                bf16x8 pf[2];
#pragma unroll
                for (int c = 0; c < 2; ++c) {
                    int chc = c * 4 + l4;
                    int slot = (chc ^ l15) & 7;
                    pf[c] = *(const bf16x8*)(&Psm[wave][l15 * 64 + slot * 8]);
                }
#pragma unroll
                for (int n = 0; n < 8; ++n) {
                    int d = n * 16 + l15;
                    bf16x8 vf[2];
#pragma unroll
                    for (int c = 0; c < 2; ++c) {
                        int ch = c * 4 + l4;
                        int slot = (ch ^ d) & 7;
                        vf[c] = *(const bf16x8*)(Vb_ + d * 64 + slot * 8);
                    }
#pragma unroll
                    for (int c = 0; c < 2; ++c)
                        o[n] = __builtin_amdgcn_mfma_f32_16x16x32_bf16(pf[c], vf[c], o[n], 0, 0, 0);
                }
            }  // active
            asm volatile("s_waitcnt lgkmcnt(0)" ::: "memory");
            __builtin_amdgcn_s_barrier();
        }

        // epilogue: O = acc / l
        float inv[4];
#pragma unroll
        for (int r = 0; r < 4; ++r) inv[r] = 1.0f / lsum[r];
#pragma unroll
        for (int n = 0; n < 8; ++n)
#pragma unroll
            for (int r = 0; r < 4; ++r) {
                int row = qr0 + l4 * 4 + r;
                O[(size_t)row * 4096 + h * 128 + n * 16 + l15] = f2b(o[n][r] * inv[r]);
            }
    }  // pass
}

// ---------------- launch ----------------
extern "C" void kernel_launch(void* const* d_in, const int* in_sizes, int n_in,
                              void* d_out, int out_size, void* d_ws, size_t ws_size,
                              hipStream_t stream) {
    const int*   pos = (const int*)d_in[0];
    const float* X   = (const float*)d_in[1];
    const float* Wq  = (const float*)d_in[2];
    const float* Wk  = (const float*)d_in[3];
    const float* Wv  = (const float*)d_in[4];
    const float* Wo  = (const float*)d_in[5];
    float* out = (float*)d_out;

    char* w = (char*)d_ws;
    u16* Xb    = (u16*)(w + 0);          //  16.78 MB
    u16* Wqkvt = (u16*)(w + 16777216);   //  50.33 MB [6144][4096]
    u16* Wot   = (u16*)(w + 67108864);   //  33.55 MB
    u16* QKV   = (u16*)(w + 100663296);  //  25.17 MB [2048][6144]
    u16* Vtb   = (u16*)(w + 125829120);  //   4.19 MB [8][128][2048]
    u16* Ob    = (u16*)(w + 130023424);  //  16.78 MB

    const float SC2 = 0.08838834764831845f * 1.4426950408889634f;  // 1/sqrt(128) * log2(e)

    // conversions / weight transposes (QKV weights packed into one [6144][4096])
    cvt_x<<<4096, 256, 0, stream>>>(X, Xb, S * D / 8);
    tconv<<<dim3(64, 64), 256, 0, stream>>>(Wq, Wqkvt, 4096, 4096);
    tconv<<<dim3(16, 64), 256, 0, stream>>>(Wk, Wqkvt + (size_t)4096 * 4096, 4096, 1024);
    tconv<<<dim3(16, 64), 256, 0, stream>>>(Wv, Wqkvt + (size_t)5120 * 4096, 4096, 1024);
    tconv<<<dim3(64, 64), 256, 0, stream>>>(Wo, Wot, 4096, 4096);

    // fused QKV projection: [2048][6144] — 256 blocks exact (8 x 32, BN=192)
    gemmP<192, true><<<256, 512, 0, stream>>>(Xb, Wqkvt, QKV, NQKV, 4096);

    // rope (scale*log2e folded into Q)
    rope2<32><<<16384, 256, 0, stream>>>(QKV, pos, SC2);
    rope2<8><<<4096, 256, 0, stream>>>(QKV + 4096, pos, 1.0f);

    // V transpose
    vtrans<<<dim3(32, 2, 8), 256, 0, stream>>>(QKV, Vtb);

    // attention (balanced pairs)
    attn3<<<512, 256, 0, stream>>>(QKV, Vtb, Ob);

    // output projection (f32 out) — 256 blocks exact (8 x 32, BN=128)
    gemmP<128, false><<<256, 512, 0, stream>>>(Ob, Wot, out, 4096, 4096);
}

// Round 10
// 367.962 us; speedup vs baseline: 1.0773x; 1.0773x over previous
//
#include <hip/hip_runtime.h>

typedef unsigned short u16;
typedef short bf16x8 __attribute__((ext_vector_type(8)));
typedef float f32x4 __attribute__((ext_vector_type(4)));

#define GLB __attribute__((address_space(1)))
#define LDSAS __attribute__((address_space(3)))

constexpr int S = 2048, D = 4096, NH = 32, NHK = 8, DHD = 128;
constexpr int NQKV = 6144;  // 4096 q + 1024 k + 1024 v

__device__ __forceinline__ u16 f2b(float f) {
    union { float f; unsigned u; } v; v.f = f;
    return (u16)((v.u + 0x7fffu + ((v.u >> 16) & 1u)) >> 16);
}
__device__ __forceinline__ float b2f(u16 b) {
    union { unsigned u; float f; } v; v.u = ((unsigned)b) << 16;
    return v.f;
}
__device__ __forceinline__ void gload16(const void* g, void* l) {
    __builtin_amdgcn_global_load_lds((const GLB unsigned int*)g,
                                     (LDSAS unsigned int*)l, 16, 0, 0);
}
#if __has_builtin(__builtin_amdgcn_exp2f)
__device__ __forceinline__ float exp2fast(float x) { return __builtin_amdgcn_exp2f(x); }
#else
__device__ __forceinline__ float exp2fast(float x) { return __expf(0.6931471805599453f * x); }
#endif

// Accurate sin/cos for large args: reduce to revolutions in [0,1), then v_sin/v_cos.
__device__ __forceinline__ void sincos_big(float ang, float* sn, float* cs) {
#if __has_builtin(__builtin_amdgcn_sinf) && __has_builtin(__builtin_amdgcn_cosf)
    float rev = ang * 0.15915494309189535f;  // 1/(2*pi)
    rev = rev - floorf(rev);                 // [0,1)
    *sn = __builtin_amdgcn_sinf(rev);
    *cs = __builtin_amdgcn_cosf(rev);
#else
    *sn = sinf(ang);
    *cs = cosf(ang);
#endif
}

// ---------------- f32 -> bf16 elementwise (8/thread) ----------------
__global__ __launch_bounds__(256) void cvt_x(const float* __restrict__ in,
                                             u16* __restrict__ out, int n8) {
    int i = blockIdx.x * 256 + threadIdx.x;
    if (i >= n8) return;
    const float4* p = (const float4*)in + (size_t)i * 2;
    float4 a = p[0], b = p[1];
    uint4 o;
    o.x = f2b(a.x) | ((unsigned)f2b(a.y) << 16);
    o.y = f2b(a.z) | ((unsigned)f2b(a.w) << 16);
    o.z = f2b(b.x) | ((unsigned)f2b(b.y) << 16);
    o.w = f2b(b.z) | ((unsigned)f2b(b.w) << 16);
    *(uint4*)(out + (size_t)i * 8) = o;
}

// ---------------- f32 [R][C] -> bf16 [C][R] ----------------
__global__ __launch_bounds__(256) void tconv(const float* __restrict__ in,
                                             u16* __restrict__ out, int R, int C) {
    __shared__ float t[64][65];
    int r0 = blockIdx.y * 64, c0 = blockIdx.x * 64;
    int tx = threadIdx.x & 63, ty = threadIdx.x >> 6;
#pragma unroll
    for (int i = 0; i < 64; i += 4)
        t[ty + i][tx] = in[(size_t)(r0 + ty + i) * C + c0 + tx];
    __syncthreads();
#pragma unroll
    for (int i = 0; i < 64; i += 4)
        out[(size_t)(c0 + ty + i) * R + r0 + tx] = f2b(t[tx][ty + i]);
}

// ---------------- bf16 V (QKV cols 5120..6143) -> Vt [hk][d][s] ----------------
__global__ __launch_bounds__(256) void vtrans(const u16* __restrict__ QKV,
                                              u16* __restrict__ Vt) {
    __shared__ u16 t[64][65];
    int hk = blockIdx.z;
    int s0 = blockIdx.x * 64, d0 = blockIdx.y * 64;
    int tx = threadIdx.x & 63, ty = threadIdx.x >> 6;
#pragma unroll
    for (int i = 0; i < 64; i += 4)
        t[ty + i][tx] = QKV[(size_t)(s0 + ty + i) * NQKV + 5120 + hk * 128 + d0 + tx];
    __syncthreads();
#pragma unroll
    for (int i = 0; i < 64; i += 4)
        Vt[(size_t)hk * (128 * 2048) + (size_t)(d0 + ty + i) * 2048 + s0 + tx] = t[tx][ty + i];
}

// ---------------- RoPE in place, bf16, stride NQKV; scale folded in ----------------
template <int NHEADS>
__global__ __launch_bounds__(256) void rope2(u16* __restrict__ T,
                                             const int* __restrict__ pos, float scale) {
    int idx = blockIdx.x * 256 + threadIdx.x;
    int d = idx & 63;
    int h = (idx >> 6) & (NHEADS - 1);
    int s = idx >> (6 + (NHEADS == 32 ? 5 : 3));
    float p = (float)pos[s];
    float inv = __expf(-(float)d * 0.14391156531310576f);  // 10000^(-d/64)
    float ang = p * inv;
    float sn, cs;
    sincos_big(ang, &sn, &cs);
    size_t base = (size_t)s * NQKV + h * 128 + d;
    float x1 = b2f(T[base]), x2 = b2f(T[base + 64]);
    T[base]      = f2b((x1 * cs - x2 * sn) * scale);
    T[base + 64] = f2b((x2 * cs + x1 * sn) * scale);
}

// ---------------- GEMM S: r5's m97-structure (best measured) + BK=64 + XOR swizzle ----------------
// 128x128 tile, BK=64, 4 waves (2x2 of 64x64), 32 KB LDS -> 3 blocks/CU at grid 768.
// Chunk swizzle cs = c ^ (row&7) on 128B rows (0 conflicts, verified r6-r9).
// Simple 2-barrier loop (m97 regime: implicit wave-level overlap does the hiding).
template <bool BF16OUT>
__global__ __launch_bounds__(256) void gemmS(const u16* __restrict__ A,
                                             const u16* __restrict__ Bt,
                                             void* __restrict__ Cout,
                                             int N, int K, int nbx) {
    __shared__ u16 Asm[128 * 64];  // 16 KB
    __shared__ u16 Bsm[128 * 64];  // 16 KB
    const int cpx = (int)gridDim.x >> 3;
    const int b = ((int)blockIdx.x & 7) * cpx + ((int)blockIdx.x >> 3);
    const int by = b / nbx, bx = b - by * nbx;
    const int m0 = by * 128, n0 = bx * 128;
    const int tid = threadIdx.x, lane = tid & 63, wave = tid >> 6;
    const int l15 = lane & 15, l4 = lane >> 4;
    const int wm = wave >> 1, wn = wave & 1;
    f32x4 acc[4][4] = {};

    for (int k0 = 0; k0 < K; k0 += 64) {
        __syncthreads();
#pragma unroll
        for (int u = 0; u < 4; ++u) {
            int s = u * 256 + tid;
            int row = s >> 3, cs = (s & 7) ^ (row & 7);
            gload16(A  + (size_t)(m0 + row) * K + k0 + cs * 8, Asm + s * 8);
            gload16(Bt + (size_t)(n0 + row) * K + k0 + cs * 8, Bsm + s * 8);
        }
        __syncthreads();
        bf16x8 af[4][2], bf[4][2];
#pragma unroll
        for (int i = 0; i < 4; ++i)
#pragma unroll
            for (int kk = 0; kk < 2; ++kk) {
                int row = wm * 64 + i * 16 + l15;
                int cc = (kk * 4 + l4) ^ (row & 7);
                af[i][kk] = *(const bf16x8*)(Asm + row * 64 + cc * 8);
            }
#pragma unroll
        for (int j = 0; j < 4; ++j)
#pragma unroll
            for (int kk = 0; kk < 2; ++kk) {
                int row = wn * 64 + j * 16 + l15;
                int cc = (kk * 4 + l4) ^ (row & 7);
                bf[j][kk] = *(const bf16x8*)(Bsm + row * 64 + cc * 8);
            }
#pragma unroll
        for (int i = 0; i < 4; ++i)
#pragma unroll
            for (int j = 0; j < 4; ++j)
#pragma unroll
                for (int kk = 0; kk < 2; ++kk)
                    acc[i][j] = __builtin_amdgcn_mfma_f32_16x16x32_bf16(af[i][kk], bf[j][kk], acc[i][j], 0, 0, 0);
    }
#pragma unroll
    for (int i = 0; i < 4; ++i)
#pragma unroll
        for (int j = 0; j < 4; ++j) {
            int col  = n0 + wn * 64 + j * 16 + l15;
            int rowb = m0 + wm * 64 + i * 16 + l4 * 4;
#pragma unroll
            for (int r = 0; r < 4; ++r) {
                if (BF16OUT)
                    ((u16*)Cout)[(size_t)(rowb + r) * N + col] = f2b(acc[i][j][r]);
                else
                    ((float*)Cout)[(size_t)(rowb + r) * N + col] = acc[i][j][r];
            }
        }
}

// ---------------- Flash attention v3: balanced tile pairs ----------------
__global__ __launch_bounds__(256) void attn3(const u16* __restrict__ QKV,
                                             const u16* __restrict__ Vt,
                                             u16* __restrict__ O) {
    __shared__ u16 Ksm[2][64 * 128];  // [kv][d-chunk swz]
    __shared__ u16 Vsm[2][128 * 64];  // [d][kv-chunk swz]
    __shared__ u16 Psm[4][16 * 64];   // per-wave P tile, swz
    const int orig = blockIdx.x;
    const int swz = (orig & 7) * 64 + (orig >> 3);   // 512 = 8*64, bijective
    const int h = swz >> 4, p = swz & 15;
    const int hk = h >> 2;
    const int tid = threadIdx.x, wave = tid >> 6, lane = tid & 63;
    const int l15 = lane & 15, l4 = lane >> 4;
    const u16* Qp = QKV + h * 128;
    const u16* Kp = QKV + 4096 + hk * 128;
    const u16* Vp = Vt + (size_t)hk * (128 * 2048);

    auto stage = [&](int kb, int b) {
#pragma unroll
        for (int it = 0; it < 4; ++it) {
            int L = it * 256 + tid;
            int krow = L >> 4, kslot = L & 15;
            int kcs = (kslot & 8) | ((kslot ^ krow) & 7);
            gload16(Kp + (size_t)(kb * 64 + krow) * NQKV + kcs * 8, &Ksm[b][L * 8]);
            int vrow = L >> 3, vslot = L & 7;
            int vcs = (vslot ^ vrow) & 7;
            gload16(Vp + (size_t)vrow * 2048 + kb * 64 + vcs * 8, &Vsm[b][L * 8]);
        }
    };

#pragma unroll 1
    for (int pass = 0; pass < 2; ++pass) {
        const int qt = pass ? p : 31 - p;
        const int qr0 = qt * 64 + wave * 16;
        const int nkb = qt + 1;

        bf16x8 qf[4];
        {
            const u16* qrow = Qp + (size_t)(qr0 + l15) * NQKV;
#pragma unroll
            for (int c = 0; c < 4; ++c)
                qf[c] = *(const bf16x8*)(qrow + c * 32 + l4 * 8);
        }
        float mrow[4], lsum[4];
#pragma unroll
        for (int r = 0; r < 4; ++r) { mrow[r] = -1e30f; lsum[r] = 0.f; }
        f32x4 o[8] = {};

        stage(0, 0);
#pragma unroll 1
        for (int kb = 0; kb < nkb; ++kb) {
            const int cur = kb & 1;
            if (kb + 1 < nkb) {
                stage(kb + 1, cur ^ 1);
                asm volatile("s_waitcnt vmcnt(8)" ::: "memory");
            } else {
                asm volatile("s_waitcnt vmcnt(0)" ::: "memory");
            }
            __builtin_amdgcn_s_barrier();

            if (kb * 64 <= qr0 + 15) {  // wave has unmasked work
                const u16* Kb_ = Ksm[cur];
                const u16* Vb_ = Vsm[cur];
                const bool diag = (kb * 64 + 63 > qr0);
                // ---- S = Q K^T (log2 domain) ----
                f32x4 sc[4] = {};
#pragma unroll
                for (int f = 0; f < 4; ++f) {
                    const int kv = f * 16 + l15;
#pragma unroll
                    for (int c = 0; c < 4; ++c) {
                        int cd = c * 4 + l4;
                        int cpos = (cd & 8) | ((cd ^ kv) & 7);
                        bf16x8 kf = *(const bf16x8*)(Kb_ + kv * 128 + cpos * 8);
                        sc[f] = __builtin_amdgcn_mfma_f32_16x16x32_bf16(qf[c], kf, sc[f], 0, 0, 0);
                    }
                }
                if (diag) {
#pragma unroll
                    for (int f = 0; f < 4; ++f) {
                        int col = kb * 64 + f * 16 + l15;
#pragma unroll
                        for (int r = 0; r < 4; ++r) {
                            int row = qr0 + l4 * 4 + r;
                            if (col > row) sc[f][r] = -1e30f;
                        }
                    }
                }
                float bm[4];
#pragma unroll
                for (int r = 0; r < 4; ++r)
                    bm[r] = fmaxf(fmaxf(sc[0][r], sc[1][r]), fmaxf(sc[2][r], sc[3][r]));
#pragma unroll
                for (int msk = 1; msk < 16; msk <<= 1)
#pragma unroll
                    for (int r = 0; r < 4; ++r) bm[r] = fmaxf(bm[r], __shfl_xor(bm[r], msk));

                bool need = false;
#pragma unroll
                for (int r = 0; r < 4; ++r) need = need || (bm[r] > mrow[r] + 8.0f);
                if (__any((int)need)) {  // T13 defer-rescale, per-row alpha
                    float al[4];
#pragma unroll
                    for (int r = 0; r < 4; ++r) {
                        float mn = fmaxf(mrow[r], bm[r]);
                        al[r] = exp2fast(mrow[r] - mn);
                        mrow[r] = mn;
                        lsum[r] *= al[r];
                    }
#pragma unroll
                    for (int n = 0; n < 8; ++n)
#pragma unroll
                        for (int r = 0; r < 4; ++r) o[n][r] *= al[r];
                }
                float rs[4] = {0.f, 0.f, 0.f, 0.f};
#pragma unroll
                for (int f = 0; f < 4; ++f) {
#pragma unroll
                    for (int r = 0; r < 4; ++r) {
                        float pw = exp2fast(sc[f][r] - mrow[r]);
                        rs[r] += pw;
                        int q = l4 * 4 + r;
                        int kvc = f * 2 + (l15 >> 3);
                        int slot = (kvc ^ q) & 7;
                        Psm[wave][q * 64 + slot * 8 + (l15 & 7)] = f2b(pw);
                    }
                }
#pragma unroll
                for (int msk = 1; msk < 16; msk <<= 1)
#pragma unroll
                    for (int r = 0; r < 4; ++r) rs[r] += __shfl_xor(rs[r], msk);
#pragma unroll
                for (int r = 0; r < 4; ++r) lsum[r] += rs[r];

                asm volatile("s_waitcnt lgkmcnt(0)" ::: "memory");
                bf16x8 pf[2];
#pragma unroll
                for (int c = 0; c < 2; ++c) {
                    int chc = c * 4 + l4;
                    int slot = (chc ^ l15) & 7;
                    pf[c] = *(const bf16x8*)(&Psm[wave][l15 * 64 + slot * 8]);
                }
#pragma unroll
                for (int n = 0; n < 8; ++n) {
                    int d = n * 16 + l15;
                    bf16x8 vf[2];
#pragma unroll
                    for (int c = 0; c < 2; ++c) {
                        int ch = c * 4 + l4;
                        int slot = (ch ^ d) & 7;
                        vf[c] = *(const bf16x8*)(Vb_ + d * 64 + slot * 8);
                    }
#pragma unroll
                    for (int c = 0; c < 2; ++c)
                        o[n] = __builtin_amdgcn_mfma_f32_16x16x32_bf16(pf[c], vf[c], o[n], 0, 0, 0);
                }
            }  // active
            asm volatile("s_waitcnt lgkmcnt(0)" ::: "memory");
            __builtin_amdgcn_s_barrier();
        }

        // epilogue: O = acc / l
        float inv[4];
#pragma unroll
        for (int r = 0; r < 4; ++r) inv[r] = 1.0f / lsum[r];
#pragma unroll
        for (int n = 0; n < 8; ++n)
#pragma unroll
            for (int r = 0; r < 4; ++r) {
                int row = qr0 + l4 * 4 + r;
                O[(size_t)row * 4096 + h * 128 + n * 16 + l15] = f2b(o[n][r] * inv[r]);
            }
    }  // pass
}

// ---------------- launch ----------------
extern "C" void kernel_launch(void* const* d_in, const int* in_sizes, int n_in,
                              void* d_out, int out_size, void* d_ws, size_t ws_size,
                              hipStream_t stream) {
    const int*   pos = (const int*)d_in[0];
    const float* X   = (const float*)d_in[1];
    const float* Wq  = (const float*)d_in[2];
    const float* Wk  = (const float*)d_in[3];
    const float* Wv  = (const float*)d_in[4];
    const float* Wo  = (const float*)d_in[5];
    float* out = (float*)d_out;

    char* w = (char*)d_ws;
    u16* Xb    = (u16*)(w + 0);          //  16.78 MB
    u16* Wqkvt = (u16*)(w + 16777216);   //  50.33 MB [6144][4096]
    u16* Wot   = (u16*)(w + 67108864);   //  33.55 MB
    u16* QKV   = (u16*)(w + 100663296);  //  25.17 MB [2048][6144]
    u16* Vtb   = (u16*)(w + 125829120);  //   4.19 MB [8][128][2048]
    u16* Ob    = (u16*)(w + 130023424);  //  16.78 MB

    const float SC2 = 0.08838834764831845f * 1.4426950408889634f;  // 1/sqrt(128) * log2(e)

    // conversions / weight transposes (QKV weights packed into one [6144][4096])
    cvt_x<<<4096, 256, 0, stream>>>(X, Xb, S * D / 8);
    tconv<<<dim3(64, 64), 256, 0, stream>>>(Wq, Wqkvt, 4096, 4096);
    tconv<<<dim3(16, 64), 256, 0, stream>>>(Wk, Wqkvt + (size_t)4096 * 4096, 4096, 1024);
    tconv<<<dim3(16, 64), 256, 0, stream>>>(Wv, Wqkvt + (size_t)5120 * 4096, 4096, 1024);
    tconv<<<dim3(64, 64), 256, 0, stream>>>(Wo, Wot, 4096, 4096);

    // fused QKV projection: [2048][6144] — 16 x 48 = 768 blocks (3/CU)
    gemmS<true><<<768, 256, 0, stream>>>(Xb, Wqkvt, QKV, NQKV, 4096, 48);

    // rope (scale*log2e folded into Q)
    rope2<32><<<16384, 256, 0, stream>>>(QKV, pos, SC2);
    rope2<8><<<4096, 256, 0, stream>>>(QKV + 4096, pos, 1.0f);

    // V transpose
    vtrans<<<dim3(32, 2, 8), 256, 0, stream>>>(QKV, Vtb);

    // attention (balanced pairs)
    attn3<<<512, 256, 0, stream>>>(QKV, Vtb, Ob);

    // output projection (f32 out) — 16 x 32 = 512 blocks (2/CU)
    gemmS<false><<<512, 256, 0, stream>>>(Ob, Wot, out, 4096, 4096, 32);
}

// Round 11
// 350.844 us; speedup vs baseline: 1.1299x; 1.0488x over previous
//
#include <hip/hip_runtime.h>

typedef unsigned short u16;
typedef short bf16x8 __attribute__((ext_vector_type(8)));
typedef float f32x4 __attribute__((ext_vector_type(4)));

#define GLB __attribute__((address_space(1)))
#define LDSAS __attribute__((address_space(3)))

constexpr int S = 2048, D = 4096, NH = 32, NHK = 8, DHD = 128;
constexpr int NQKV = 6144;  // 4096 q + 1024 k + 1024 v

__device__ __forceinline__ u16 f2b(float f) {
    union { float f; unsigned u; } v; v.f = f;
    return (u16)((v.u + 0x7fffu + ((v.u >> 16) & 1u)) >> 16);
}
__device__ __forceinline__ float b2f(u16 b) {
    union { unsigned u; float f; } v; v.u = ((unsigned)b) << 16;
    return v.f;
}
__device__ __forceinline__ void gload16(const void* g, void* l) {
    __builtin_amdgcn_global_load_lds((const GLB unsigned int*)g,
                                     (LDSAS unsigned int*)l, 16, 0, 0);
}
#if __has_builtin(__builtin_amdgcn_exp2f)
__device__ __forceinline__ float exp2fast(float x) { return __builtin_amdgcn_exp2f(x); }
#else
__device__ __forceinline__ float exp2fast(float x) { return __expf(0.6931471805599453f * x); }
#endif

// Accurate sin/cos for large args: reduce to revolutions in [0,1), then v_sin/v_cos.
__device__ __forceinline__ void sincos_big(float ang, float* sn, float* cs) {
#if __has_builtin(__builtin_amdgcn_sinf) && __has_builtin(__builtin_amdgcn_cosf)
    float rev = ang * 0.15915494309189535f;  // 1/(2*pi)
    rev = rev - floorf(rev);                 // [0,1)
    *sn = __builtin_amdgcn_sinf(rev);
    *cs = __builtin_amdgcn_cosf(rev);
#else
    *sn = sinf(ang);
    *cs = cosf(ang);
#endif
}

// ---------------- f32 -> bf16 elementwise (8/thread) ----------------
__global__ __launch_bounds__(256) void cvt_x(const float* __restrict__ in,
                                             u16* __restrict__ out, int n8) {
    int i = blockIdx.x * 256 + threadIdx.x;
    if (i >= n8) return;
    const float4* p = (const float4*)in + (size_t)i * 2;
    float4 a = p[0], b = p[1];
    uint4 o;
    o.x = f2b(a.x) | ((unsigned)f2b(a.y) << 16);
    o.y = f2b(a.z) | ((unsigned)f2b(a.w) << 16);
    o.z = f2b(b.x) | ((unsigned)f2b(b.y) << 16);
    o.w = f2b(b.z) | ((unsigned)f2b(b.w) << 16);
    *(uint4*)(out + (size_t)i * 8) = o;
}

// ---------------- f32 [R][C] -> bf16 [C][R] ----------------
__global__ __launch_bounds__(256) void tconv(const float* __restrict__ in,
                                             u16* __restrict__ out, int R, int C) {
    __shared__ float t[64][65];
    int r0 = blockIdx.y * 64, c0 = blockIdx.x * 64;
    int tx = threadIdx.x & 63, ty = threadIdx.x >> 6;
#pragma unroll
    for (int i = 0; i < 64; i += 4)
        t[ty + i][tx] = in[(size_t)(r0 + ty + i) * C + c0 + tx];
    __syncthreads();
#pragma unroll
    for (int i = 0; i < 64; i += 4)
        out[(size_t)(c0 + ty + i) * R + r0 + tx] = f2b(t[tx][ty + i]);
}

// ---------------- bf16 V (QKV cols 5120..6143) -> Vt [hk][d][s] ----------------
__global__ __launch_bounds__(256) void vtrans(const u16* __restrict__ QKV,
                                              u16* __restrict__ Vt) {
    __shared__ u16 t[64][65];
    int hk = blockIdx.z;
    int s0 = blockIdx.x * 64, d0 = blockIdx.y * 64;
    int tx = threadIdx.x & 63, ty = threadIdx.x >> 6;
#pragma unroll
    for (int i = 0; i < 64; i += 4)
        t[ty + i][tx] = QKV[(size_t)(s0 + ty + i) * NQKV + 5120 + hk * 128 + d0 + tx];
    __syncthreads();
#pragma unroll
    for (int i = 0; i < 64; i += 4)
        Vt[(size_t)hk * (128 * 2048) + (size_t)(d0 + ty + i) * 2048 + s0 + tx] = t[tx][ty + i];
}

// ---------------- RoPE in place, bf16, stride NQKV; scale folded in ----------------
template <int NHEADS>
__global__ __launch_bounds__(256) void rope2(u16* __restrict__ T,
                                             const int* __restrict__ pos, float scale) {
    int idx = blockIdx.x * 256 + threadIdx.x;
    int d = idx & 63;
    int h = (idx >> 6) & (NHEADS - 1);
    int s = idx >> (6 + (NHEADS == 32 ? 5 : 3));
    float p = (float)pos[s];
    float inv = __expf(-(float)d * 0.14391156531310576f);  // 10000^(-d/64)
    float ang = p * inv;
    float sn, cs;
    sincos_big(ang, &sn, &cs);
    size_t base = (size_t)s * NQKV + h * 128 + d;
    float x1 = b2f(T[base]), x2 = b2f(T[base + 64]);
    T[base]      = f2b((x1 * cs - x2 * sn) * scale);
    T[base + 64] = f2b((x2 * cs + x1 * sn) * scale);
}

// ---------------- GEMM S: m97-structure, BK=64, XOR swizzle (best measured, r10) ----------------
template <bool BF16OUT>
__global__ __launch_bounds__(256) void gemmS(const u16* __restrict__ A,
                                             const u16* __restrict__ Bt,
                                             void* __restrict__ Cout,
                                             int N, int K, int nbx) {
    __shared__ u16 Asm[128 * 64];  // 16 KB
    __shared__ u16 Bsm[128 * 64];  // 16 KB
    const int cpx = (int)gridDim.x >> 3;
    const int b = ((int)blockIdx.x & 7) * cpx + ((int)blockIdx.x >> 3);
    const int by = b / nbx, bx = b - by * nbx;
    const int m0 = by * 128, n0 = bx * 128;
    const int tid = threadIdx.x, lane = tid & 63, wave = tid >> 6;
    const int l15 = lane & 15, l4 = lane >> 4;
    const int wm = wave >> 1, wn = wave & 1;
    f32x4 acc[4][4] = {};

    for (int k0 = 0; k0 < K; k0 += 64) {
        __syncthreads();
#pragma unroll
        for (int u = 0; u < 4; ++u) {
            int s = u * 256 + tid;
            int row = s >> 3, cs = (s & 7) ^ (row & 7);
            gload16(A  + (size_t)(m0 + row) * K + k0 + cs * 8, Asm + s * 8);
            gload16(Bt + (size_t)(n0 + row) * K + k0 + cs * 8, Bsm + s * 8);
        }
        __syncthreads();
        bf16x8 af[4][2], bf[4][2];
#pragma unroll
        for (int i = 0; i < 4; ++i)
#pragma unroll
            for (int kk = 0; kk < 2; ++kk) {
                int row = wm * 64 + i * 16 + l15;
                int cc = (kk * 4 + l4) ^ (row & 7);
                af[i][kk] = *(const bf16x8*)(Asm + row * 64 + cc * 8);
            }
#pragma unroll
        for (int j = 0; j < 4; ++j)
#pragma unroll
            for (int kk = 0; kk < 2; ++kk) {
                int row = wn * 64 + j * 16 + l15;
                int cc = (kk * 4 + l4) ^ (row & 7);
                bf[j][kk] = *(const bf16x8*)(Bsm + row * 64 + cc * 8);
            }
#pragma unroll
        for (int i = 0; i < 4; ++i)
#pragma unroll
            for (int j = 0; j < 4; ++j)
#pragma unroll
                for (int kk = 0; kk < 2; ++kk)
                    acc[i][j] = __builtin_amdgcn_mfma_f32_16x16x32_bf16(af[i][kk], bf[j][kk], acc[i][j], 0, 0, 0);
    }
#pragma unroll
    for (int i = 0; i < 4; ++i)
#pragma unroll
        for (int j = 0; j < 4; ++j) {
            int col  = n0 + wn * 64 + j * 16 + l15;
            int rowb = m0 + wm * 64 + i * 16 + l4 * 4;
#pragma unroll
            for (int r = 0; r < 4; ++r) {
                if (BF16OUT)
                    ((u16*)Cout)[(size_t)(rowb + r) * N + col] = f2b(acc[i][j][r]);
                else
                    ((float*)Cout)[(size_t)(rowb + r) * N + col] = acc[i][j][r];
            }
        }
}

// ---------------- Flash attention v4: balanced pairs + deferred softmax reductions ----------------
// lsum is a PER-LANE partial (reduced once in the epilogue); row-max check is
// lane-local with __any trigger (P <= 2^8 bound preserved) — removes ~64
// cross-lane ops per 64-kv step from the critical path.
__global__ __launch_bounds__(256) void attn3(const u16* __restrict__ QKV,
                                             const u16* __restrict__ Vt,
                                             u16* __restrict__ O) {
    __shared__ u16 Ksm[2][64 * 128];  // [kv][d-chunk swz]
    __shared__ u16 Vsm[2][128 * 64];  // [d][kv-chunk swz]
    __shared__ u16 Psm[4][16 * 64];   // per-wave P tile, swz
    const int orig = blockIdx.x;
    const int swz = (orig & 7) * 64 + (orig >> 3);   // 512 = 8*64, bijective
    const int h = swz >> 4, p = swz & 15;
    const int hk = h >> 2;
    const int tid = threadIdx.x, wave = tid >> 6, lane = tid & 63;
    const int l15 = lane & 15, l4 = lane >> 4;
    const u16* Qp = QKV + h * 128;
    const u16* Kp = QKV + 4096 + hk * 128;
    const u16* Vp = Vt + (size_t)hk * (128 * 2048);

    auto stage = [&](int kb, int b) {
#pragma unroll
        for (int it = 0; it < 4; ++it) {
            int L = it * 256 + tid;
            int krow = L >> 4, kslot = L & 15;
            int kcs = (kslot & 8) | ((kslot ^ krow) & 7);
            gload16(Kp + (size_t)(kb * 64 + krow) * NQKV + kcs * 8, &Ksm[b][L * 8]);
            int vrow = L >> 3, vslot = L & 7;
            int vcs = (vslot ^ vrow) & 7;
            gload16(Vp + (size_t)vrow * 2048 + kb * 64 + vcs * 8, &Vsm[b][L * 8]);
        }
    };

#pragma unroll 1
    for (int pass = 0; pass < 2; ++pass) {
        const int qt = pass ? p : 31 - p;
        const int qr0 = qt * 64 + wave * 16;
        const int nkb = qt + 1;

        bf16x8 qf[4];
        {
            const u16* qrow = Qp + (size_t)(qr0 + l15) * NQKV;
#pragma unroll
            for (int c = 0; c < 4; ++c)
                qf[c] = *(const bf16x8*)(qrow + c * 32 + l4 * 8);
        }
        float mrow[4], lsum[4];  // lsum = per-lane partial row sum
#pragma unroll
        for (int r = 0; r < 4; ++r) { mrow[r] = -1e30f; lsum[r] = 0.f; }
        f32x4 o[8] = {};

        stage(0, 0);
#pragma unroll 1
        for (int kb = 0; kb < nkb; ++kb) {
            const int cur = kb & 1;
            if (kb + 1 < nkb) {
                stage(kb + 1, cur ^ 1);
                asm volatile("s_waitcnt vmcnt(8)" ::: "memory");
            } else {
                asm volatile("s_waitcnt vmcnt(0)" ::: "memory");
            }
            __builtin_amdgcn_s_barrier();

            if (kb * 64 <= qr0 + 15) {  // wave has unmasked work
                const u16* Kb_ = Ksm[cur];
                const u16* Vb_ = Vsm[cur];
                const bool diag = (kb * 64 + 63 > qr0);
                // ---- S = Q K^T (log2 domain) ----
                f32x4 sc[4] = {};
#pragma unroll
                for (int f = 0; f < 4; ++f) {
                    const int kv = f * 16 + l15;
#pragma unroll
                    for (int c = 0; c < 4; ++c) {
                        int cd = c * 4 + l4;
                        int cpos = (cd & 8) | ((cd ^ kv) & 7);
                        bf16x8 kf = *(const bf16x8*)(Kb_ + kv * 128 + cpos * 8);
                        sc[f] = __builtin_amdgcn_mfma_f32_16x16x32_bf16(qf[c], kf, sc[f], 0, 0, 0);
                    }
                }
                if (diag) {
#pragma unroll
                    for (int f = 0; f < 4; ++f) {
                        int col = kb * 64 + f * 16 + l15;
#pragma unroll
                        for (int r = 0; r < 4; ++r) {
                            int row = qr0 + l4 * 4 + r;
                            if (col > row) sc[f][r] = -1e30f;
                        }
                    }
                }
                // lane-local max + defer trigger (P <= 2^8 preserved via __any)
                float bm[4];
#pragma unroll
                for (int r = 0; r < 4; ++r)
                    bm[r] = fmaxf(fmaxf(sc[0][r], sc[1][r]), fmaxf(sc[2][r], sc[3][r]));
                bool need = false;
#pragma unroll
                for (int r = 0; r < 4; ++r) need = need || (bm[r] > mrow[r] + 8.0f);
                if (__any((int)need)) {
#pragma unroll
                    for (int msk = 1; msk < 16; msk <<= 1)
#pragma unroll
                        for (int r = 0; r < 4; ++r) bm[r] = fmaxf(bm[r], __shfl_xor(bm[r], msk));
                    float al[4];
#pragma unroll
                    for (int r = 0; r < 4; ++r) {
                        float mn = fmaxf(mrow[r], bm[r]);
                        al[r] = exp2fast(mrow[r] - mn);
                        mrow[r] = mn;
                        lsum[r] *= al[r];  // per-lane partial scales uniformly
                    }
#pragma unroll
                    for (int n = 0; n < 8; ++n)
#pragma unroll
                        for (int r = 0; r < 4; ++r) o[n][r] *= al[r];
                }
                // P = exp2(S - m): accumulate per-lane partial sums only
#pragma unroll
                for (int f = 0; f < 4; ++f) {
#pragma unroll
                    for (int r = 0; r < 4; ++r) {
                        float pw = exp2fast(sc[f][r] - mrow[r]);
                        lsum[r] += pw;
                        int q = l4 * 4 + r;
                        int kvc = f * 2 + (l15 >> 3);
                        int slot = (kvc ^ q) & 7;
                        Psm[wave][q * 64 + slot * 8 + (l15 & 7)] = f2b(pw);
                    }
                }

                asm volatile("s_waitcnt lgkmcnt(0)" ::: "memory");
                bf16x8 pf[2];
#pragma unroll
                for (int c = 0; c < 2; ++c) {
                    int chc = c * 4 + l4;
                    int slot = (chc ^ l15) & 7;
                    pf[c] = *(const bf16x8*)(&Psm[wave][l15 * 64 + slot * 8]);
                }
#pragma unroll
                for (int n = 0; n < 8; ++n) {
                    int d = n * 16 + l15;
                    bf16x8 vf[2];
#pragma unroll
                    for (int c = 0; c < 2; ++c) {
                        int ch = c * 4 + l4;
                        int slot = (ch ^ d) & 7;
                        vf[c] = *(const bf16x8*)(Vb_ + d * 64 + slot * 8);
                    }
#pragma unroll
                    for (int c = 0; c < 2; ++c)
                        o[n] = __builtin_amdgcn_mfma_f32_16x16x32_bf16(pf[c], vf[c], o[n], 0, 0, 0);
                }
            }  // active
            asm volatile("s_waitcnt lgkmcnt(0)" ::: "memory");
            __builtin_amdgcn_s_barrier();
        }

        // epilogue: reduce per-lane lsum partials across the 16-lane group, then O = acc / l
#pragma unroll
        for (int msk = 1; msk < 16; msk <<= 1)
#pragma unroll
            for (int r = 0; r < 4; ++r) lsum[r] += __shfl_xor(lsum[r], msk);
        float inv[4];
#pragma unroll
        for (int r = 0; r < 4; ++r) inv[r] = 1.0f / lsum[r];
#pragma unroll
        for (int n = 0; n < 8; ++n)
#pragma unroll
            for (int r = 0; r < 4; ++r) {
                int row = qr0 + l4 * 4 + r;
                O[(size_t)row * 4096 + h * 128 + n * 16 + l15] = f2b(o[n][r] * inv[r]);
            }
    }  // pass
}

// ---------------- launch ----------------
extern "C" void kernel_launch(void* const* d_in, const int* in_sizes, int n_in,
                              void* d_out, int out_size, void* d_ws, size_t ws_size,
                              hipStream_t stream) {
    const int*   pos = (const int*)d_in[0];
    const float* X   = (const float*)d_in[1];
    const float* Wq  = (const float*)d_in[2];
    const float* Wk  = (const float*)d_in[3];
    const float* Wv  = (const float*)d_in[4];
    const float* Wo  = (const float*)d_in[5];
    float* out = (float*)d_out;

    char* w = (char*)d_ws;
    u16* Xb    = (u16*)(w + 0);          //  16.78 MB
    u16* Wqkvt = (u16*)(w + 16777216);   //  50.33 MB [6144][4096]
    u16* Wot   = (u16*)(w + 67108864);   //  33.55 MB
    u16* QKV   = (u16*)(w + 100663296);  //  25.17 MB [2048][6144]
    u16* Vtb   = (u16*)(w + 125829120);  //   4.19 MB [8][128][2048]
    u16* Ob    = (u16*)(w + 130023424);  //  16.78 MB

    const float SC2 = 0.08838834764831845f * 1.4426950408889634f;  // 1/sqrt(128) * log2(e)

    // conversions / weight transposes (QKV weights packed into one [6144][4096])
    cvt_x<<<4096, 256, 0, stream>>>(X, Xb, S * D / 8);
    tconv<<<dim3(64, 64), 256, 0, stream>>>(Wq, Wqkvt, 4096, 4096);
    tconv<<<dim3(16, 64), 256, 0, stream>>>(Wk, Wqkvt + (size_t)4096 * 4096, 4096, 1024);
    tconv<<<dim3(16, 64), 256, 0, stream>>>(Wv, Wqkvt + (size_t)5120 * 4096, 4096, 1024);
    tconv<<<dim3(64, 64), 256, 0, stream>>>(Wo, Wot, 4096, 4096);

    // fused QKV projection: [2048][6144] — 16 x 48 = 768 blocks (3/CU)
    gemmS<true><<<768, 256, 0, stream>>>(Xb, Wqkvt, QKV, NQKV, 4096, 48);

    // rope (scale*log2e folded into Q)
    rope2<32><<<16384, 256, 0, stream>>>(QKV, pos, SC2);
    rope2<8><<<4096, 256, 0, stream>>>(QKV + 4096, pos, 1.0f);

    // V transpose
    vtrans<<<dim3(32, 2, 8), 256, 0, stream>>>(QKV, Vtb);

    // attention (balanced pairs, deferred softmax)
    attn3<<<512, 256, 0, stream>>>(QKV, Vtb, Ob);

    // output projection (f32 out) — 16 x 32 = 512 blocks (2/CU)
    gemmS<false><<<512, 256, 0, stream>>>(Ob, Wot, out, 4096, 4096, 32);
}